// Round 1
// baseline (72.716 us; speedup 1.0000x reference)
//
#include <hip/hip_runtime.h>

// PCEN: out = (x / (FLOOR + ema(x))^alpha + delta)^(1/root) - delta^(1/root)
// ema: h[t] = s*x[t] + (1-s)*h[t-1], h[-1] = x[0]  (so ema[0] = x[0])
//
// Parallelization: chunk T into CHUNK-length pieces; each thread computes one
// (b, chunk, c) sequence with a WARM-step warm-up (0.96^256 ~ 3e-5 residual
// influence of the true initial state -> well under tolerance).

#define S_COEF 0.04f
#define OMS    0.96f
#define FLOOR_EPS 1e-6f

constexpr int B_DIM = 64;
constexpr int T_DIM = 4096;
constexpr int C_DIM = 128;
constexpr int CHUNK = 256;
constexpr int WARM  = 256;
constexpr int NCHUNK = T_DIM / CHUNK; // 16

__global__ __launch_bounds__(256) void pcen_kernel(
    const float* __restrict__ x,
    const float* __restrict__ alpha,
    const float* __restrict__ delta,
    const float* __restrict__ root,
    float* __restrict__ out) {
  const int tid   = blockIdx.x * 256 + threadIdx.x;
  const int c     = tid & (C_DIM - 1);
  const int rest  = tid >> 7;              // / C_DIM
  const int chunk = rest & (NCHUNK - 1);
  const int b     = rest >> 4;             // / NCHUNK

  // per-channel params
  const float a     = fminf(alpha[c], 1.0f);
  const float d     = delta[c];
  const float r     = fmaxf(root[c], 1.0f);
  const float oor   = 1.0f / r;
  const float droot = __expf(oor * __logf(d));

  const int t0 = chunk * CHUNK;
  const int tw = (t0 >= WARM) ? (t0 - WARM) : 0;  // == 0 only for chunk 0 (exact)
  const float* __restrict__ xp = x + ((size_t)b * T_DIM + tw) * C_DIM + c;

  // h_prev = x[tw]; first update at t=tw yields h = x[tw] (matches reference
  // exactly when tw == 0: ema[0] = x[0]).
  float h = *xp;
  const int nwarm = t0 - tw;
  #pragma unroll 8
  for (int i = 0; i < nwarm; ++i) {
    const float xv = *xp; xp += C_DIM;
    h = fmaf(OMS, h, S_COEF * xv);
  }

  float* __restrict__ op = out + ((size_t)b * T_DIM + t0) * C_DIM + c;
  #pragma unroll 4
  for (int i = 0; i < CHUNK; ++i) {
    const float xv = *xp; xp += C_DIM;
    h = fmaf(OMS, h, S_COEF * xv);
    const float e     = FLOOR_EPS + h;
    const float scale = __expf(-a * __logf(e));      // (floor+ema)^-alpha
    const float base  = fmaf(xv, scale, d);          // x*(...)^-alpha + delta
    const float o     = __expf(oor * __logf(base)) - droot;
    __builtin_nontemporal_store(o, op);              // don't evict input from L3
    op += C_DIM;
  }
}

extern "C" void kernel_launch(void* const* d_in, const int* in_sizes, int n_in,
                              void* d_out, int out_size, void* d_ws, size_t ws_size,
                              hipStream_t stream) {
  const float* x     = (const float*)d_in[0];
  const float* alpha = (const float*)d_in[1];
  const float* delta = (const float*)d_in[2];
  const float* root  = (const float*)d_in[3];
  float* out = (float*)d_out;

  const int total_threads = B_DIM * NCHUNK * C_DIM; // 131072
  pcen_kernel<<<total_threads / 256, 256, 0, stream>>>(x, alpha, delta, root, out);
}